// Round 4
// baseline (648.449 us; speedup 1.0000x reference)
//
#include <hip/hip_runtime.h>
#include <cstdint>
#include <cstddef>

#define N_NODES 8192
#define N_EDGES 262144
#define INPUT_DIM 512
#define HIDDEN 128
#define ALPHA 0.5f
#define EOS 1e-10f
#define BCAP 128
#define LDA 40   // bf16 row stride: 80 B = 5*16 (b128-aligned), banks 2-way max (free)

typedef float v4 __attribute__((ext_vector_type(4)));
typedef __attribute__((ext_vector_type(8))) short short8;
typedef __attribute__((ext_vector_type(4))) float floatx4;

__device__ inline unsigned short f2bf(float x) {
    unsigned u = __builtin_bit_cast(unsigned, x);
    return (unsigned short)((u + 0x7FFFu + ((u >> 16) & 1u)) >> 16);
}
__device__ inline unsigned pack2(float a, float b) {
    return (unsigned)f2bf(a) | ((unsigned)f2bf(b) << 16);
}

// K1 (MFMA): g[n] = sum_k relu(F[n]·W[k] + bemb[k]) * (Wedge[k] + Wedge[128+k])
// 256 blocks x 128 threads; block = 32 nodes x 128 hidden, K-loop 16 x 32.
// Also zeroes cnt[] (saves a memset dispatch).
__global__ __launch_bounds__(128) void k1_g(
    const float* __restrict__ F, const float* __restrict__ W,
    const float* __restrict__ bemb, const float* __restrict__ Wedge,
    float* __restrict__ g, int* __restrict__ cnt)
{
    __shared__ unsigned short As[32 * LDA];
    __shared__ unsigned short Bs[128 * LDA];
    int tid = threadIdx.x;
    int gt = blockIdx.x * 128 + tid;
    if (gt < N_NODES) cnt[gt] = 0;

    int node0 = blockIdx.x * 32;
    int lane = tid & 63, wave = tid >> 6;
    int ml = lane & 15, q = lane >> 4;

    floatx4 acc[8];
#pragma unroll
    for (int f = 0; f < 8; f++) acc[f] = 0.f;

    for (int s = 0; s < 16; s++) {
        int d0 = s * 32;
        // stage A tile: 32 nodes x 32 d = 256 float4, 2/thread
#pragma unroll
        for (int j = 0; j < 2; j++) {
            int qi = j * 128 + tid;
            int row = qi >> 3, dq = (qi & 7) * 4;
            float4 v = *(const float4*)&F[(size_t)(node0 + row) * INPUT_DIM + d0 + dq];
            uint2 p; p.x = pack2(v.x, v.y); p.y = pack2(v.z, v.w);
            *(uint2*)&As[row * LDA + dq] = p;
        }
        // stage B tile: 128 k x 32 d = 1024 float4, 8/thread
#pragma unroll
        for (int j = 0; j < 8; j++) {
            int qi = j * 128 + tid;
            int row = qi >> 3, dq = (qi & 7) * 4;
            float4 v = *(const float4*)&W[(size_t)row * INPUT_DIM + d0 + dq];
            uint2 p; p.x = pack2(v.x, v.y); p.y = pack2(v.z, v.w);
            *(uint2*)&Bs[row * LDA + dq] = p;
        }
        __syncthreads();
        // A frag: A[m=ml][k=q*8+j]
        short8 a = *(const short8*)&As[(wave * 16 + ml) * LDA + q * 8];
#pragma unroll
        for (int f = 0; f < 8; f++) {
            short8 b = *(const short8*)&Bs[(f * 16 + ml) * LDA + q * 8];
            acc[f] = __builtin_amdgcn_mfma_f32_16x16x32_bf16(a, b, acc[f], 0, 0, 0);
        }
        __syncthreads();
    }
    // epilogue: C/D col=ml (hidden), row=q*4+reg (node). relu+dot, reduce over cols.
    float s0 = 0.f, s1 = 0.f, s2 = 0.f, s3 = 0.f;
#pragma unroll
    for (int f = 0; f < 8; f++) {
        int n = f * 16 + ml;
        float u = Wedge[n] + Wedge[HIDDEN + n];
        float bb = bemb[n];
        float h0 = acc[f][0] + bb; s0 += (h0 > 0.f ? h0 : 0.f) * u;
        float h1 = acc[f][1] + bb; s1 += (h1 > 0.f ? h1 : 0.f) * u;
        float h2 = acc[f][2] + bb; s2 += (h2 > 0.f ? h2 : 0.f) * u;
        float h3 = acc[f][3] + bb; s3 += (h3 > 0.f ? h3 : 0.f) * u;
    }
#pragma unroll
    for (int m = 1; m < 16; m <<= 1) {
        s0 += __shfl_xor(s0, m, 64);
        s1 += __shfl_xor(s1, m, 64);
        s2 += __shfl_xor(s2, m, 64);
        s3 += __shfl_xor(s3, m, 64);
    }
    if (ml == 0) {
        int node = node0 + wave * 16 + q * 4;
        g[node + 0] = s0; g[node + 1] = s1; g[node + 2] = s2; g[node + 3] = s3;
    }
}

// K2: per-edge weight compute + bucket scatter.
__global__ __launch_bounds__(256) void k_edge(
    const int* __restrict__ edges, const float* __restrict__ noise,
    const float* __restrict__ g, const float* __restrict__ bedge,
    float* __restrict__ wlp, float* __restrict__ whp,
    int* __restrict__ cnt, int* __restrict__ bucket)
{
    int i = blockIdx.x * 256 + threadIdx.x;
    int e0 = edges[i], e1 = edges[N_EDGES + i];
    float raw = 0.5f * (g[e0] + g[e1]) + bedge[0];
    float eps = -0.9998f * noise[i] + 0.9999f;
    float gate = logf(eps) - log1pf(-eps) + raw;
    float w = 1.f / (1.f + expf(-gate));
    wlp[i] = w;
    whp[i] = 1.f - w;
    int pos = atomicAdd(&cnt[e0], 1);
    if (pos < BCAP) bucket[e0 * BCAP + pos] = i;
}

// K3: winner resolution (last-write-wins = max edge idx) + degrees -> inv factors.
// Rewrites bucket entries: winner -> (col<<18)|idx (>=0), loser -> -1.
// 2 rows per block (256 threads: 128 per row).
__global__ __launch_bounds__(256) void k_deginv(
    const int* __restrict__ edges, const float* __restrict__ wlp,
    const float* __restrict__ whp, const int* __restrict__ cnt,
    int* __restrict__ bucket, float* __restrict__ inv_lp, float* __restrict__ inv_hp)
{
    __shared__ int cols[2][BCAP];
    __shared__ int eidx[2][BCAP];
    __shared__ float plp[4], php[4];
    int tid = threadIdx.x;
    int half = tid >> 7, lt = tid & 127;
    int r = blockIdx.x * 2 + half;
    int d = cnt[r]; if (d > BCAP) d = BCAP;
    int i = -1, c = -1;
    if (lt < d) {
        i = bucket[r * BCAP + lt];
        c = edges[N_EDGES + i];
        cols[half][lt] = c;
        eidx[half][lt] = i;
    }
    __syncthreads();
    float sl = 0.f, sh = 0.f;
    if (lt < d) {
        bool win = true;
        for (int j = 0; j < d; j++)
            if (cols[half][j] == c && eidx[half][j] > i) { win = false; break; }
        int packv = -1;
        if (win) { sl = wlp[i]; sh = whp[i]; packv = (c << 18) | i; }
        bucket[r * BCAP + lt] = packv;
    }
#pragma unroll
    for (int m = 1; m < 64; m <<= 1) {
        sl += __shfl_xor(sl, m, 64);
        sh += __shfl_xor(sh, m, 64);
    }
    int wv = tid >> 6;
    if ((tid & 63) == 0) { plp[wv] = sl; php[wv] = sh; }
    __syncthreads();
    if (lt == 0) {
        float l = plp[half * 2] + plp[half * 2 + 1];
        float h = php[half * 2] + php[half * 2 + 1];
        inv_lp[r] = 1.f / (sqrtf(l + 1.f) + EOS);
        inv_hp[r] = 1.f / (sqrtf(h + 1.f) + EOS);
    }
}

// K4: compose one output row in LDS (zeros + diag + pre-resolved edge cells),
// stream out with NT float4 stores. blockIdx: bit0 = matrix, rest = row.
__global__ __launch_bounds__(256) void k_fill(
    const float* __restrict__ wlp, const float* __restrict__ whp,
    const int* __restrict__ cnt, const int* __restrict__ bucket,
    const float* __restrict__ inv_lp, const float* __restrict__ inv_hp,
    float* __restrict__ LP, float* __restrict__ HP)
{
    __shared__ float row[N_NODES];
    int b = blockIdx.x, m = b & 1, r = b >> 1, tid = threadIdx.x;
    v4* rv = (v4*)row;
#pragma unroll
    for (int i = 0; i < 8; i++) rv[tid + i * 256] = 0.f;

    int d = cnt[r]; if (d > BCAP) d = BCAP;
    const float* wsrc = m ? whp : wlp;
    const float* isrc = m ? inv_hp : inv_lp;
    float ir = isrc[r];
    int pv = -1;
    if (tid < d) pv = bucket[r * BCAP + tid];
    __syncthreads();
    if (tid == 0) row[r] = m ? 1.0f : ir * ir;   // non-edge diagonal background
    __syncthreads();
    if (pv >= 0) {
        int c = pv >> 18, i = pv & 0x3FFFF;
        float w = wsrc[i], ic = isrc[c];
        float diag = (c == r) ? 1.f : 0.f;
        row[c] = m ? (diag - (w + diag) * ir * ic * ALPHA)
                   : ((w + diag) * ir * ic);
    }
    __syncthreads();
    v4* dst = (v4*)((m ? HP : LP) + (size_t)r * N_NODES);
#pragma unroll
    for (int i = 0; i < 8; i++)
        __builtin_nontemporal_store(rv[tid + i * 256], &dst[tid + i * 256]);
}

extern "C" void kernel_launch(void* const* d_in, const int* in_sizes, int n_in,
                              void* d_out, int out_size, void* d_ws, size_t ws_size,
                              hipStream_t stream) {
    const float* F     = (const float*)d_in[0];
    const float* W     = (const float*)d_in[1];
    const float* bemb  = (const float*)d_in[2];
    const float* Wedge = (const float*)d_in[3];
    const float* bedge = (const float*)d_in[4];
    const float* noise = (const float*)d_in[5];
    const int*   edges = (const int*)d_in[6];

    const size_t N2 = (size_t)N_NODES * N_NODES;
    float* out = (float*)d_out;
    float* LP  = out;
    float* HP  = out + N2;
    float* wlp = HP + N2;
    float* whp = wlp + N_EDGES;

    // ws layout: g(32K) | cnt(32K) | inv_lp(32K) | inv_hp(32K) | bucket(4MB)
    char* ws = (char*)d_ws;
    float* g      = (float*)(ws);
    int*   cnt    = (int*)  (ws + 32768);
    float* inv_lp = (float*)(ws + 65536);
    float* inv_hp = (float*)(ws + 98304);
    int*   bucket = (int*)  (ws + 131072);

    k1_g<<<256, 128, 0, stream>>>(F, W, bemb, Wedge, g, cnt);
    k_edge<<<N_EDGES / 256, 256, 0, stream>>>(edges, noise, g, bedge,
                                              wlp, whp, cnt, bucket);
    k_deginv<<<N_NODES / 2, 256, 0, stream>>>(edges, wlp, whp, cnt, bucket,
                                              inv_lp, inv_hp);
    k_fill<<<2 * N_NODES, 256, 0, stream>>>(wlp, whp, cnt, bucket,
                                            inv_lp, inv_hp, LP, HP);
}

// Round 5
// 614.894 us; speedup vs baseline: 1.0546x; 1.0546x over previous
//
#include <hip/hip_runtime.h>
#include <cstdint>
#include <cstddef>

#define N_NODES 8192
#define N_EDGES 262144
#define INPUT_DIM 512
#define HIDDEN 128
#define ALPHA 0.5f
#define EOS 1e-10f
#define BCAP 128
#define LDA 40   // bf16 LDS row stride: 80 B (16B-aligned for b128 reads)

typedef float v4 __attribute__((ext_vector_type(4)));
typedef __attribute__((ext_vector_type(8))) short short8;
typedef __attribute__((ext_vector_type(4))) float floatx4;

__device__ inline unsigned short f2bf(float x) {
    unsigned u = __builtin_bit_cast(unsigned, x);
    return (unsigned short)((u + 0x7FFFu + ((u >> 16) & 1u)) >> 16);
}
__device__ inline unsigned pack2(float a, float b) {
    return (unsigned)f2bf(a) | ((unsigned)f2bf(b) << 16);
}

// K1 (MFMA, pipelined): g[n] = sum_k relu(F[n]·W[k]+bemb[k]) * (Wedge[k]+Wedge[128+k])
// 256 blocks x 256 threads (4 waves). Block = 32 nodes x 128 hidden, 16 K-steps of 32.
// wave: strip = wave&1 (16 nodes), hq = wave>>1 (64 hidden = 4 MFMA tiles).
// Register-prefetch: next step's global loads issued before the MFMA phase.
__global__ __launch_bounds__(256) void k1_g(
    const float* __restrict__ F, const float* __restrict__ W,
    const float* __restrict__ bemb, const float* __restrict__ Wedge,
    float* __restrict__ g, int* __restrict__ cnt)
{
    __shared__ unsigned short As[32 * LDA];
    __shared__ unsigned short Bs[128 * LDA];
    __shared__ float part[4][16];
    int tid = threadIdx.x;
    int gt = blockIdx.x * 256 + tid;
    if (gt < N_NODES) cnt[gt] = 0;

    int node0 = blockIdx.x * 32;
    int lane = tid & 63, wave = tid >> 6;
    int ml = lane & 15, q = lane >> 4;
    int strip = wave & 1, hq = wave >> 1;

    // staging: A = 256 float4 (1/thread), B = 1024 float4 (4/thread)
    int arow = tid >> 3, ac4 = (tid & 7) * 4;
    const float* Fp = &F[(size_t)(node0 + arow) * INPUT_DIM + ac4];
    const float* Wp = &W[(size_t)arow * INPUT_DIM + ac4];

    float4 aR = *(const float4*)Fp;
    float4 bR0 = *(const float4*)(Wp + (size_t)(0 * 32) * INPUT_DIM);
    float4 bR1 = *(const float4*)(Wp + (size_t)(1 * 32) * INPUT_DIM);
    float4 bR2 = *(const float4*)(Wp + (size_t)(2 * 32) * INPUT_DIM);
    float4 bR3 = *(const float4*)(Wp + (size_t)(3 * 32) * INPUT_DIM);

    floatx4 acc[4];
#pragma unroll
    for (int j = 0; j < 4; j++) acc[j] = 0.f;

    for (int s = 0; s < 16; s++) {
        { uint2 p; p.x = pack2(aR.x, aR.y); p.y = pack2(aR.z, aR.w);
          *(uint2*)&As[arow * LDA + ac4] = p; }
        { uint2 p; p.x = pack2(bR0.x, bR0.y); p.y = pack2(bR0.z, bR0.w);
          *(uint2*)&Bs[(0 * 32 + arow) * LDA + ac4] = p; }
        { uint2 p; p.x = pack2(bR1.x, bR1.y); p.y = pack2(bR1.z, bR1.w);
          *(uint2*)&Bs[(1 * 32 + arow) * LDA + ac4] = p; }
        { uint2 p; p.x = pack2(bR2.x, bR2.y); p.y = pack2(bR2.z, bR2.w);
          *(uint2*)&Bs[(2 * 32 + arow) * LDA + ac4] = p; }
        { uint2 p; p.x = pack2(bR3.x, bR3.y); p.y = pack2(bR3.z, bR3.w);
          *(uint2*)&Bs[(3 * 32 + arow) * LDA + ac4] = p; }
        __syncthreads();
        if (s < 15) {                       // prefetch next step; in flight during MFMAs
            int off = (s + 1) * 32;
            aR  = *(const float4*)(Fp + off);
            bR0 = *(const float4*)(Wp + off + (size_t)(0 * 32) * INPUT_DIM);
            bR1 = *(const float4*)(Wp + off + (size_t)(1 * 32) * INPUT_DIM);
            bR2 = *(const float4*)(Wp + off + (size_t)(2 * 32) * INPUT_DIM);
            bR3 = *(const float4*)(Wp + off + (size_t)(3 * 32) * INPUT_DIM);
        }
        short8 a = *(const short8*)&As[(strip * 16 + ml) * LDA + q * 8];
#pragma unroll
        for (int j = 0; j < 4; j++) {
            short8 b = *(const short8*)&Bs[((hq * 4 + j) * 16 + ml) * LDA + q * 8];
            acc[j] = __builtin_amdgcn_mfma_f32_16x16x32_bf16(a, b, acc[j], 0, 0, 0);
        }
        __syncthreads();
    }
    // epilogue: C/D col=ml (hidden-in-tile), row=q*4+reg (node-in-strip)
    float sr[4] = {0.f, 0.f, 0.f, 0.f};
#pragma unroll
    for (int j = 0; j < 4; j++) {
        int hcol = (hq * 4 + j) * 16 + ml;
        float u = Wedge[hcol] + Wedge[HIDDEN + hcol];
        float bb = bemb[hcol];
#pragma unroll
        for (int rg = 0; rg < 4; rg++) {
            float h = acc[j][rg] + bb;
            sr[rg] += (h > 0.f ? h : 0.f) * u;
        }
    }
#pragma unroll
    for (int m = 1; m < 16; m <<= 1) {
#pragma unroll
        for (int rg = 0; rg < 4; rg++) sr[rg] += __shfl_xor(sr[rg], m, 16);
    }
    if (ml == 0) {
#pragma unroll
        for (int rg = 0; rg < 4; rg++) part[wave][q * 4 + rg] = sr[rg];
    }
    __syncthreads();
    if (tid < 32) {
        int st = tid >> 4, ni = tid & 15;
        g[node0 + st * 16 + ni] = part[st][ni] + part[st + 2][ni];
    }
}

// K2: per-edge weight compute + bucket scatter.
__global__ __launch_bounds__(256) void k_edge(
    const int* __restrict__ edges, const float* __restrict__ noise,
    const float* __restrict__ g, const float* __restrict__ bedge,
    float* __restrict__ wlp, float* __restrict__ whp,
    int* __restrict__ cnt, int* __restrict__ bucket)
{
    int i = blockIdx.x * 256 + threadIdx.x;
    int e0 = edges[i], e1 = edges[N_EDGES + i];
    float raw = 0.5f * (g[e0] + g[e1]) + bedge[0];
    float eps = -0.9998f * noise[i] + 0.9999f;
    float gate = logf(eps) - log1pf(-eps) + raw;
    float w = 1.f / (1.f + expf(-gate));
    wlp[i] = w;
    whp[i] = 1.f - w;
    int pos = atomicAdd(&cnt[e0], 1);
    if (pos < BCAP) bucket[e0 * BCAP + pos] = i;
}

// K3: winner resolution (last-write-wins = max edge idx) + degrees -> inv factors.
// Rewrites bucket: winner -> col (>=0), loser -> -1; writes compact w values.
__global__ __launch_bounds__(256) void k_deginv(
    const int* __restrict__ edges, const float* __restrict__ wlp,
    const float* __restrict__ whp, const int* __restrict__ cnt,
    int* __restrict__ bucket, float* __restrict__ bval_lp, float* __restrict__ bval_hp,
    float* __restrict__ inv_lp, float* __restrict__ inv_hp)
{
    __shared__ int cols[2][BCAP];
    __shared__ int eidx[2][BCAP];
    __shared__ float plp[4], php[4];
    int tid = threadIdx.x;
    int half = tid >> 7, lt = tid & 127;
    int r = blockIdx.x * 2 + half;
    int d = cnt[r]; if (d > BCAP) d = BCAP;
    int i = -1, c = -1;
    if (lt < d) {
        i = bucket[r * BCAP + lt];
        c = edges[N_EDGES + i];
        cols[half][lt] = c;
        eidx[half][lt] = i;
    }
    __syncthreads();
    float sl = 0.f, sh = 0.f;
    if (lt < d) {
        bool win = true;
        for (int j = 0; j < d; j++)
            if (cols[half][j] == c && eidx[half][j] > i) { win = false; break; }
        if (win) {
            sl = wlp[i]; sh = whp[i];
            bucket[r * BCAP + lt] = c;
            bval_lp[r * BCAP + lt] = sl;
            bval_hp[r * BCAP + lt] = sh;
        } else {
            bucket[r * BCAP + lt] = -1;
        }
    }
#pragma unroll
    for (int m = 1; m < 64; m <<= 1) {
        sl += __shfl_xor(sl, m, 64);
        sh += __shfl_xor(sh, m, 64);
    }
    int wv = tid >> 6;
    if ((tid & 63) == 0) { plp[wv] = sl; php[wv] = sh; }
    __syncthreads();
    if (lt == 0) {
        float l = plp[half * 2] + plp[half * 2 + 1];
        float h = php[half * 2] + php[half * 2 + 1];
        inv_lp[r] = 1.f / (sqrtf(l + 1.f) + EOS);
        inv_hp[r] = 1.f / (sqrtf(h + 1.f) + EOS);
    }
}

// K4: one block per ROW, emits BOTH LP and HP rows. Col-bitmap + compact value
// list in LDS; zero chunks NT-stored straight from registers (no row image).
__global__ __launch_bounds__(256) void k_fill(
    const int* __restrict__ cnt, const int* __restrict__ bucket,
    const float* __restrict__ bval_lp, const float* __restrict__ bval_hp,
    const float* __restrict__ inv_lp, const float* __restrict__ inv_hp,
    float* __restrict__ LP, float* __restrict__ HP)
{
    __shared__ unsigned bm[256];          // 8192 col bits
    __shared__ int   s_col[BCAP + 1];
    __shared__ float s_vlp[BCAP + 1];
    __shared__ float s_vhp[BCAP + 1];
    __shared__ int   s_d;
    int r = blockIdx.x, tid = threadIdx.x;
    bm[tid] = 0;
    int d = cnt[r]; if (d > BCAP) d = BCAP;
    float irl = inv_lp[r], irh = inv_hp[r];
    __syncthreads();
    int c = -1;
    if (tid < d) c = bucket[r * BCAP + tid];
    if (tid < d) s_col[tid] = c;
    if (c >= 0) {
        float w_lp = bval_lp[r * BCAP + tid];
        float w_hp = bval_hp[r * BCAP + tid];
        float icl = inv_lp[c], ich = inv_hp[c];
        float diag = (c == r) ? 1.f : 0.f;
        s_vlp[tid] = (w_lp + diag) * irl * icl;
        s_vhp[tid] = diag - (w_hp + diag) * irh * ich * ALPHA;
        atomicOr(&bm[c >> 5], 1u << (c & 31));
    }
    __syncthreads();
    if (tid == 0) {
        int dd = d;
        if (!((bm[r >> 5] >> (r & 31)) & 1u)) {   // no self-edge: background diagonal
            s_col[dd] = r; s_vlp[dd] = irl * irl; s_vhp[dd] = 1.0f;
            bm[r >> 5] |= 1u << (r & 31);
            dd++;
        }
        s_d = dd;
    }
    __syncthreads();
    int dd = s_d;
    float* LPr = LP + (size_t)r * N_NODES;
    float* HPr = HP + (size_t)r * N_NODES;
#pragma unroll
    for (int i = 0; i < 8; i++) {
        int ch = i * 256 + tid;               // chunk of 4 cols
        unsigned nib = (bm[ch >> 3] >> ((ch & 7) * 4)) & 0xFu;
        v4 lp = 0.f, hp = 0.f;
        if (nib) {
            for (int e = 0; e < dd; e++) {
                int cc = s_col[e];
                if ((cc >> 2) == ch) {
                    int sl = cc & 3;
                    ((float*)&lp)[sl] = s_vlp[e];
                    ((float*)&hp)[sl] = s_vhp[e];
                }
            }
        }
        __builtin_nontemporal_store(lp, (v4*)&LPr[ch * 4]);
        __builtin_nontemporal_store(hp, (v4*)&HPr[ch * 4]);
    }
}

extern "C" void kernel_launch(void* const* d_in, const int* in_sizes, int n_in,
                              void* d_out, int out_size, void* d_ws, size_t ws_size,
                              hipStream_t stream) {
    const float* F     = (const float*)d_in[0];
    const float* W     = (const float*)d_in[1];
    const float* bemb  = (const float*)d_in[2];
    const float* Wedge = (const float*)d_in[3];
    const float* bedge = (const float*)d_in[4];
    const float* noise = (const float*)d_in[5];
    const int*   edges = (const int*)d_in[6];

    const size_t N2 = (size_t)N_NODES * N_NODES;
    float* out = (float*)d_out;
    float* LP  = out;
    float* HP  = out + N2;
    float* wlp = HP + N2;
    float* whp = wlp + N_EDGES;

    // ws: g(32K) | cnt(32K) | inv_lp(32K) | inv_hp(32K) | bucket(4M) | bval_lp(4M) | bval_hp(4M)
    char* ws = (char*)d_ws;
    float* g       = (float*)(ws);
    int*   cnt     = (int*)  (ws + 32768);
    float* inv_lp  = (float*)(ws + 65536);
    float* inv_hp  = (float*)(ws + 98304);
    int*   bucket  = (int*)  (ws + 131072);
    float* bval_lp = (float*)(ws + 131072 + (size_t)N_NODES * BCAP * 4);
    float* bval_hp = (float*)(ws + 131072 + 2 * (size_t)N_NODES * BCAP * 4);

    k1_g<<<256, 256, 0, stream>>>(F, W, bemb, Wedge, g, cnt);
    k_edge<<<N_EDGES / 256, 256, 0, stream>>>(edges, noise, g, bedge,
                                              wlp, whp, cnt, bucket);
    k_deginv<<<N_NODES / 2, 256, 0, stream>>>(edges, wlp, whp, cnt, bucket,
                                              bval_lp, bval_hp, inv_lp, inv_hp);
    k_fill<<<N_NODES, 256, 0, stream>>>(cnt, bucket, bval_lp, bval_hp,
                                        inv_lp, inv_hp, LP, HP);
}

// Round 6
// 610.118 us; speedup vs baseline: 1.0628x; 1.0078x over previous
//
#include <hip/hip_runtime.h>
#include <cstdint>
#include <cstddef>

#define N_NODES 8192
#define N_EDGES 262144
#define INPUT_DIM 512
#define HIDDEN 128
#define ALPHA 0.5f
#define EOS 1e-10f
#define BCAP 128

typedef float v4 __attribute__((ext_vector_type(4)));
typedef __attribute__((ext_vector_type(8))) short short8;
typedef __attribute__((ext_vector_type(4))) float floatx4;

__device__ inline unsigned short f2bf(float x) {
    unsigned u = __builtin_bit_cast(unsigned, x);
    return (unsigned short)((u + 0x7FFFu + ((u >> 16) & 1u)) >> 16);
}

// K0: convert F (8192x512) and W (128x512) to bf16; zero cnt. 4096 blocks x 256.
__global__ __launch_bounds__(256) void k0_conv(
    const float* __restrict__ F, const float* __restrict__ W,
    unsigned short* __restrict__ F16, unsigned short* __restrict__ W16,
    int* __restrict__ cnt)
{
    int t = blockIdx.x * 256 + threadIdx.x;     // 1,048,576 threads
    if (t < N_NODES) cnt[t] = 0;
    {   // F: 1,048,576 float4s, one per thread
        float4 v = *(const float4*)&F[(size_t)t * 4];
        uint2 p;
        p.x = (unsigned)f2bf(v.x) | ((unsigned)f2bf(v.y) << 16);
        p.y = (unsigned)f2bf(v.z) | ((unsigned)f2bf(v.w) << 16);
        *(uint2*)&F16[(size_t)t * 4] = p;
    }
    if (t < 16384) {                             // W: 16384 float4s
        float4 v = *(const float4*)&W[(size_t)t * 4];
        uint2 p;
        p.x = (unsigned)f2bf(v.x) | ((unsigned)f2bf(v.y) << 16);
        p.y = (unsigned)f2bf(v.z) | ((unsigned)f2bf(v.w) << 16);
        *(uint2*)&W16[(size_t)t * 4] = p;
    }
}

// K1: g[n] = sum_h relu(F[n]·W[h]+bemb[h]) * (Wedge[h]+Wedge[128+h])
// 512 blocks x 256 threads (4 waves). Block = 16 nodes; wave = 32 hidden (2 MFMA
// tiles) x full K. Fragments loaded DIRECTLY from global bf16 (A and B frags are
// 8 consecutive k of one row) — no LDS, no barriers in the K-loop.
__global__ __launch_bounds__(256) void k1_g(
    const unsigned short* __restrict__ F16, const unsigned short* __restrict__ W16,
    const float* __restrict__ bemb, const float* __restrict__ Wedge,
    float* __restrict__ g)
{
    __shared__ float part[4][16];
    int tid = threadIdx.x;
    int lane = tid & 63, wave = tid >> 6;
    int ml = lane & 15, q = lane >> 4;
    int node0 = blockIdx.x * 16;
    int h0 = wave * 32;

    const unsigned short* Ap  = &F16[(size_t)(node0 + ml) * INPUT_DIM + q * 8];
    const unsigned short* Bp0 = &W16[(size_t)(h0 + ml) * INPUT_DIM + q * 8];
    const unsigned short* Bp1 = &W16[(size_t)(h0 + 16 + ml) * INPUT_DIM + q * 8];

    floatx4 acc0 = 0.f, acc1 = 0.f;
#pragma unroll 4
    for (int s = 0; s < 16; s++) {
        short8 a  = *(const short8*)(Ap  + s * 32);
        short8 b0 = *(const short8*)(Bp0 + s * 32);
        short8 b1 = *(const short8*)(Bp1 + s * 32);
        acc0 = __builtin_amdgcn_mfma_f32_16x16x32_bf16(a, b0, acc0, 0, 0, 0);
        acc1 = __builtin_amdgcn_mfma_f32_16x16x32_bf16(a, b1, acc1, 0, 0, 0);
    }
    // C/D: col(=hidden-in-tile)=ml, row(=node-in-tile)=q*4+reg
    float sr[4] = {0.f, 0.f, 0.f, 0.f};
#pragma unroll
    for (int t = 0; t < 2; t++) {
        int h = h0 + t * 16 + ml;
        float uu = Wedge[h] + Wedge[HIDDEN + h];
        float bb = bemb[h];
        floatx4 ac = t ? acc1 : acc0;
#pragma unroll
        for (int rg = 0; rg < 4; rg++) {
            float hv = ac[rg] + bb;
            sr[rg] += (hv > 0.f ? hv : 0.f) * uu;
        }
    }
#pragma unroll
    for (int m = 1; m < 16; m <<= 1) {
#pragma unroll
        for (int rg = 0; rg < 4; rg++) sr[rg] += __shfl_xor(sr[rg], m, 64);
    }
    if (ml == 0) {
#pragma unroll
        for (int rg = 0; rg < 4; rg++) part[wave][q * 4 + rg] = sr[rg];
    }
    __syncthreads();
    if (tid < 16)
        g[node0 + tid] = part[0][tid] + part[1][tid] + part[2][tid] + part[3][tid];
}

// K2: per-edge weight + packed bucket scatter: (col<<18)|idx and w as one int2.
__global__ __launch_bounds__(256) void k_edge(
    const int* __restrict__ edges, const float* __restrict__ noise,
    const float* __restrict__ g, const float* __restrict__ bedge,
    float* __restrict__ wlp, float* __restrict__ whp,
    int* __restrict__ cnt, int2* __restrict__ buck)
{
    int i = blockIdx.x * 256 + threadIdx.x;
    int e0 = edges[i], e1 = edges[N_EDGES + i];
    float raw = 0.5f * (g[e0] + g[e1]) + bedge[0];
    float eps = -0.9998f * noise[i] + 0.9999f;
    float gate = logf(eps) - log1pf(-eps) + raw;
    float w = 1.f / (1.f + expf(-gate));
    wlp[i] = w;
    whp[i] = 1.f - w;
    int pos = atomicAdd(&cnt[e0], 1);
    if (pos < BCAP) {
        int2 pw;
        pw.x = (e1 << 18) | i;
        pw.y = __builtin_bit_cast(int, w);
        buck[e0 * BCAP + pos] = pw;
    }
}

// K3: winner resolution + degrees -> inv factors. 2 rows/block.
// Winner = max packed value among same col (col in high bits, idx in low).
// Rewrites buck.x: winner -> col (>=0), loser -> -1 (w stays in buck.y).
__global__ __launch_bounds__(256) void k_deginv(
    const int* __restrict__ cnt, int2* __restrict__ buck,
    float* __restrict__ inv_lp, float* __restrict__ inv_hp)
{
    __shared__ int s_pv[2][BCAP];
    __shared__ float plp[4], php[4];
    int tid = threadIdx.x;
    int half = tid >> 7, lt = tid & 127;
    int r = blockIdx.x * 2 + half;
    int d = cnt[r]; if (d > BCAP) d = BCAP;
    int2 pw; pw.x = -1; pw.y = 0;
    if (lt < d) {
        pw = buck[r * BCAP + lt];
        s_pv[half][lt] = pw.x;
    }
    __syncthreads();
    float sl = 0.f, sh = 0.f;
    if (lt < d) {
        int pv = pw.x, c = pv >> 18;
        bool win = true;
        for (int j = 0; j < d; j++) {
            int o = s_pv[half][j];
            if ((o >> 18) == c && o > pv) { win = false; break; }
        }
        if (win) {
            float w = __builtin_bit_cast(float, pw.y);
            sl = w; sh = 1.f - w;
            pw.x = c;
        } else {
            pw.x = -1;
        }
        buck[r * BCAP + lt] = pw;
    }
#pragma unroll
    for (int m = 1; m < 64; m <<= 1) {
        sl += __shfl_xor(sl, m, 64);
        sh += __shfl_xor(sh, m, 64);
    }
    int wv = tid >> 6;
    if ((tid & 63) == 0) { plp[wv] = sl; php[wv] = sh; }
    __syncthreads();
    if (lt == 0) {
        float l = plp[half * 2] + plp[half * 2 + 1];
        float h = php[half * 2] + php[half * 2 + 1];
        inv_lp[r] = 1.f / (sqrtf(l + 1.f) + EOS);
        inv_hp[r] = 1.f / (sqrtf(h + 1.f) + EOS);
    }
}

// K4: one block per row, emits BOTH LP and HP rows. Col-bitmap + compact value
// list in LDS; zero chunks NT-stored straight from registers.
__global__ __launch_bounds__(256) void k_fill(
    const int* __restrict__ cnt, const int2* __restrict__ buck,
    const float* __restrict__ inv_lp, const float* __restrict__ inv_hp,
    float* __restrict__ LP, float* __restrict__ HP)
{
    __shared__ unsigned bm[256];          // 8192 col bits
    __shared__ int   s_col[BCAP + 1];
    __shared__ float s_vlp[BCAP + 1];
    __shared__ float s_vhp[BCAP + 1];
    __shared__ int   s_d;
    int r = blockIdx.x, tid = threadIdx.x;
    bm[tid] = 0;
    int d = cnt[r]; if (d > BCAP) d = BCAP;
    float irl = inv_lp[r], irh = inv_hp[r];
    __syncthreads();
    int c = -1;
    if (tid < d) {
        int2 pw = buck[r * BCAP + tid];
        c = pw.x;
        s_col[tid] = c;
        if (c >= 0) {
            float w = __builtin_bit_cast(float, pw.y);
            float icl = inv_lp[c], ich = inv_hp[c];
            float diag = (c == r) ? 1.f : 0.f;
            s_vlp[tid] = (w + diag) * irl * icl;
            s_vhp[tid] = diag - ((1.f - w) + diag) * irh * ich * ALPHA;
            atomicOr(&bm[c >> 5], 1u << (c & 31));
        }
    }
    __syncthreads();
    if (tid == 0) {
        int dd = d;
        if (!((bm[r >> 5] >> (r & 31)) & 1u)) {   // no self-edge: background diagonal
            s_col[dd] = r; s_vlp[dd] = irl * irl; s_vhp[dd] = 1.0f;
            bm[r >> 5] |= 1u << (r & 31);
            dd++;
        }
        s_d = dd;
    }
    __syncthreads();
    int dd = s_d;
    float* LPr = LP + (size_t)r * N_NODES;
    float* HPr = HP + (size_t)r * N_NODES;
#pragma unroll
    for (int i = 0; i < 8; i++) {
        int ch = i * 256 + tid;               // chunk of 4 cols
        unsigned nib = (bm[ch >> 3] >> ((ch & 7) * 4)) & 0xFu;
        v4 lp = 0.f, hp = 0.f;
        if (nib) {
            for (int e = 0; e < dd; e++) {
                int cc = s_col[e];
                if (cc >= 0 && (cc >> 2) == ch) {
                    int sl = cc & 3;
                    ((float*)&lp)[sl] = s_vlp[e];
                    ((float*)&hp)[sl] = s_vhp[e];
                }
            }
        }
        __builtin_nontemporal_store(lp, (v4*)&LPr[ch * 4]);
        __builtin_nontemporal_store(hp, (v4*)&HPr[ch * 4]);
    }
}

extern "C" void kernel_launch(void* const* d_in, const int* in_sizes, int n_in,
                              void* d_out, int out_size, void* d_ws, size_t ws_size,
                              hipStream_t stream) {
    const float* F     = (const float*)d_in[0];
    const float* W     = (const float*)d_in[1];
    const float* bemb  = (const float*)d_in[2];
    const float* Wedge = (const float*)d_in[3];
    const float* bedge = (const float*)d_in[4];
    const float* noise = (const float*)d_in[5];
    const int*   edges = (const int*)d_in[6];

    const size_t N2 = (size_t)N_NODES * N_NODES;
    float* out = (float*)d_out;
    float* LP  = out;
    float* HP  = out + N2;
    float* wlp = HP + N2;
    float* whp = wlp + N_EDGES;

    // ws: g(32K) | cnt(32K) | inv_lp(32K) | inv_hp(32K) | buck(8M) | F16(8M) | W16(128K)
    char* ws = (char*)d_ws;
    float* g      = (float*)(ws);
    int*   cnt    = (int*)  (ws + 32768);
    float* inv_lp = (float*)(ws + 65536);
    float* inv_hp = (float*)(ws + 98304);
    int2*  buck   = (int2*) (ws + 131072);
    unsigned short* F16 = (unsigned short*)(ws + 131072 + (size_t)N_NODES * BCAP * 8);
    unsigned short* W16 = F16 + (size_t)N_NODES * INPUT_DIM;

    k0_conv<<<4096, 256, 0, stream>>>(F, W, F16, W16, cnt);
    k1_g<<<512, 256, 0, stream>>>(F16, W16, bemb, Wedge, g);
    k_edge<<<N_EDGES / 256, 256, 0, stream>>>(edges, noise, g, bedge,
                                              wlp, whp, cnt, buck);
    k_deginv<<<N_NODES / 2, 256, 0, stream>>>(cnt, buck, inv_lp, inv_hp);
    k_fill<<<N_NODES, 256, 0, stream>>>(cnt, buck, inv_lp, inv_hp, LP, HP);
}